// Round 11
// baseline (83.155 us; speedup 1.0000x reference)
//
#include <hip/hip_runtime.h>
#include <hip/hip_bf16.h>
#include <math.h>

#define NDIM 4096
#define MDIM 4096
#define LDIM 512
#define KDIM 1024

typedef short bf16x8 __attribute__((ext_vector_type(8)));
typedef float f32x4 __attribute__((ext_vector_type(4)));

// ---------------------------------------------------------------------------
// Fully fused: per block, per K-tile, the 512 threads COMPUTE the A/B panel
// values (s*w_l*cos/sin(<f_l,x>) etc.) on the VALU directly into swizzled LDS,
// then MFMA-consume them. No staging globals, no vmcnt ledger, 1 barrier/tile.
// Geometry = R9 (verified): 256x256 tile, BK=64, 8 waves 2Mx4N, wave 128x64.
// K-tile t: cols 64t..64t+63 = cos(l=64t..) for t<8, sin(l=64(t-8)..) for t>=8.
// Producer: thread -> (rg=tid>>3: rows rg+{0,64,128,192}, gi=tid&7: l-octet),
// write bf16x8 at byte (16gi)^((rg&7)<<4) of row -- same involution as reads.
// ---------------------------------------------------------------------------
__global__ __launch_bounds__(512, 2) void fused_kernel(
    const float* __restrict__ x, const float* __restrict__ y,
    const float* __restrict__ freqs, const float* __restrict__ lam,
    const float* __restrict__ var, float* __restrict__ C) {
  __shared__ __align__(16) short Al[2][2][128 * 64];   // [buf][slab][128x64]
  __shared__ __align__(16) short Bl[2][2][128 * 64];
  __shared__ float red[8];
  __shared__ float s_sh;

  int bid  = blockIdx.x;                  // 0..255
  int brow = (bid >> 4) * 256;
  int bcol = (bid & 15) * 256;

  int tid  = threadIdx.x;
  int lane = tid & 63;
  int wid  = tid >> 6;                    // 0..7
  int wm   = wid >> 2;                    // 0..1
  int wn   = wid & 3;                     // 0..3

  // producer mapping
  int gi   = tid & 7;                     // l-octet: l_local = 8*gi..8*gi+7
  int rg   = tid >> 3;                    // 0..63; rows rg + 64*j
  int wr_x = (gi * 16) ^ ((rg & 7) << 4); // swizzled byte-in-row

  // consumer ds_read offsets (verbatim R9)
  int fr    = lane & 15;
  int u     = (lane >> 4) * 16;
  int xs    = (fr & 7) << 4;
  int swzk0 = u ^ xs;
  int swzk1 = (64 + u) ^ xs;
  int aRow  = fr * 128;
  int bRow  = ((wn & 1) * 64 + fr) * 128;

  // ---- prologue: s = |var| / sum_l exp(-0.5*lam_l) ----
  float wv_ = expf(-0.5f * lam[tid]);     // tid < 512 = LDIM
  float v_ = wv_;
  #pragma unroll
  for (int off = 32; off > 0; off >>= 1) v_ += __shfl_down(v_, off, 64);
  if (lane == 0) red[wid] = v_;
  __syncthreads();
  if (tid == 0) {
    float tt = 0.f;
    #pragma unroll
    for (int i = 0; i < 8; ++i) tt += red[i];
    s_sh = fabsf(var[0]) / tt;
  }
  __syncthreads();
  float s_loc = s_sh;

  f32x4 acc[8][4] = {};
  bf16x8 a00, a01, a10, a11, a20, a21, a30, a31;
  bf16x8 b00, b01, b10, b11, c00, c01, c10, c11;

#define COMPUTE_P(T1, DB, ARR, PTS, BASE, WEIGHTED) {                        \
    int l0_ = (((T1) & 7) << 6) + (gi << 3);                                 \
    float FX[8], FY[8], FZ[8], WL[8];                                        \
    _Pragma("unroll")                                                        \
    for (int i = 0; i < 8; ++i) {                                            \
      int li = l0_ + i;                                                      \
      FX[i] = freqs[3 * li]; FY[i] = freqs[3 * li + 1];                      \
      FZ[i] = freqs[3 * li + 2];                                             \
      WL[i] = (WEIGHTED) ? s_loc * expf(-0.5f * lam[li]) : 1.0f;             \
    }                                                                        \
    _Pragma("unroll")                                                        \
    for (int j = 0; j < 4; ++j) {                                            \
      int r_ = rg + 64 * j;                                                  \
      const float* pp = (PTS) + 3 * (size_t)((BASE) + r_);                   \
      float p0 = pp[0], p1 = pp[1], p2 = pp[2];                              \
      bf16x8 o;                                                              \
      _Pragma("unroll")                                                      \
      for (int i = 0; i < 8; ++i) {                                          \
        float px = p0 * FX[i] + p1 * FY[i] + p2 * FZ[i];                     \
        float sn, cs; __sincosf(px, &sn, &cs);                               \
        float vv = (((T1) >= 8) ? sn : cs) * WL[i];                          \
        union { __hip_bfloat16 h; short u2; } cv;                            \
        cv.h = __float2bfloat16(vv); o[i] = cv.u2;                           \
      }                                                                      \
      *(bf16x8*)((char*)&ARR[DB][j >> 1][0] +                                \
                 (rg + 64 * (j & 1)) * 128 + wr_x) = o;                      \
    } }

#define COMPUTE_A(T1, DB) COMPUTE_P(T1, DB, Al, x, brow, 1)
#define COMPUTE_B(T1, DB) COMPUTE_P(T1, DB, Bl, y, bcol, 0)

#define AREAD(BUF, MH) {                                                     \
    const char* P = (const char*)&Al[BUF][wm][0] + aRow + (MH) * 8192;       \
    a00 = *(const bf16x8*)(P + 0    + swzk0);                                \
    a01 = *(const bf16x8*)(P + 0    + swzk1);                                \
    a10 = *(const bf16x8*)(P + 2048 + swzk0);                                \
    a11 = *(const bf16x8*)(P + 2048 + swzk1);                                \
    a20 = *(const bf16x8*)(P + 4096 + swzk0);                                \
    a21 = *(const bf16x8*)(P + 4096 + swzk1);                                \
    a30 = *(const bf16x8*)(P + 6144 + swzk0);                                \
    a31 = *(const bf16x8*)(P + 6144 + swzk1); }

#define BREAD(BUF, NH, S) {                                                  \
    const char* P = (const char*)&Bl[BUF][wn >> 1][0] + bRow + (NH) * 4096;  \
    S##00 = *(const bf16x8*)(P + 0    + swzk0);                              \
    S##01 = *(const bf16x8*)(P + 0    + swzk1);                              \
    S##10 = *(const bf16x8*)(P + 2048 + swzk0);                              \
    S##11 = *(const bf16x8*)(P + 2048 + swzk1); }

#define MF(M, N, AF, BF)                                                     \
  acc[M][N] = __builtin_amdgcn_mfma_f32_16x16x32_bf16(AF, BF, acc[M][N], 0, 0, 0);

#define QMFMA(MH, NH, S)                                                     \
  __builtin_amdgcn_s_setprio(1);                                             \
  MF((MH)*4+0, (NH)*2+0, a00, S##00) MF((MH)*4+0, (NH)*2+1, a00, S##10)      \
  MF((MH)*4+1, (NH)*2+0, a10, S##00) MF((MH)*4+1, (NH)*2+1, a10, S##10)      \
  MF((MH)*4+2, (NH)*2+0, a20, S##00) MF((MH)*4+2, (NH)*2+1, a20, S##10)      \
  MF((MH)*4+3, (NH)*2+0, a30, S##00) MF((MH)*4+3, (NH)*2+1, a30, S##10)      \
  MF((MH)*4+0, (NH)*2+0, a01, S##01) MF((MH)*4+0, (NH)*2+1, a01, S##11)      \
  MF((MH)*4+1, (NH)*2+0, a11, S##01) MF((MH)*4+1, (NH)*2+1, a11, S##11)      \
  MF((MH)*4+2, (NH)*2+0, a21, S##01) MF((MH)*4+2, (NH)*2+1, a21, S##11)      \
  MF((MH)*4+3, (NH)*2+0, a31, S##01) MF((MH)*4+3, (NH)*2+1, a31, S##11)      \
  __builtin_amdgcn_s_setprio(0);

  // ---- tile 0 panels ----
  COMPUTE_A(0, 0);
  COMPUTE_B(0, 0);
  __syncthreads();

  // ---- main loop: 1 barrier per tile; producer for t+1 interleaved ----
  for (int t = 0; t < 15; ++t) {
    int buf = t & 1;
    int nb  = buf ^ 1;
    int t1  = t + 1;
    COMPUTE_A(t1, nb);
    AREAD(buf, 0); BREAD(buf, 0, b); BREAD(buf, 1, c);
    QMFMA(0, 0, b)
    QMFMA(0, 1, c)
    COMPUTE_B(t1, nb);
    AREAD(buf, 1);
    QMFMA(1, 1, c)
    QMFMA(1, 0, b)
    __syncthreads();
  }
  // ---- t = 15 (no producer) ----
  {
    int buf = 1;
    AREAD(buf, 0); BREAD(buf, 0, b); BREAD(buf, 1, c);
    QMFMA(0, 0, b)
    QMFMA(0, 1, c)
    AREAD(buf, 1);
    QMFMA(1, 1, c)
    QMFMA(1, 0, b)
  }

  // ---- epilogue: C/D layout col=lane&15, row=(lane>>4)*4+j (R9 verbatim) ----
  int crow = brow + wm * 128 + (lane >> 4) * 4;
  int ccol = bcol + wn * 64 + (lane & 15);
  #pragma unroll
  for (int mi = 0; mi < 8; ++mi)
    #pragma unroll
    for (int n = 0; n < 4; ++n)
      #pragma unroll
      for (int j = 0; j < 4; ++j)
        C[(size_t)(crow + mi * 16 + j) * MDIM + (ccol + n * 16)] = acc[mi][n][j];
}

extern "C" void kernel_launch(void* const* d_in, const int* in_sizes, int n_in,
                              void* d_out, int out_size, void* d_ws, size_t ws_size,
                              hipStream_t stream) {
  const float* x     = (const float*)d_in[0];
  const float* y     = (const float*)d_in[1];
  const float* freqs = (const float*)d_in[2];
  const float* lam   = (const float*)d_in[3];
  const float* var   = (const float*)d_in[4];
  float* out = (float*)d_out;

  hipLaunchKernelGGL(fused_kernel, dim3((NDIM / 256) * (MDIM / 256)), dim3(512),
                     0, stream, x, y, freqs, lam, var, out);
}

// Round 12
// 60.934 us; speedup vs baseline: 1.3647x; 1.3647x over previous
//
#include <hip/hip_runtime.h>
#include <hip/hip_bf16.h>
#include <math.h>

#define NDIM 4096
#define MDIM 4096
#define LDIM 512
#define KDIM 1024
#define NT   16     // K-tiles of BK=64
#define PH_ROWS 8

typedef short bf16x8 __attribute__((ext_vector_type(8)));
typedef float f32x4 __attribute__((ext_vector_type(4)));

#define GLOBAL_AS __attribute__((address_space(1)))
#define LDS_AS __attribute__((address_space(3)))

__device__ __align__(16) __hip_bfloat16 g_A[(size_t)NDIM * KDIM];
// B transposed-blocked: g_Bt[k>>3][col][k&7], elem = (k>>3)*MDIM*8 + col*8 + (k&7)
__device__ __align__(16) __hip_bfloat16 g_Bt[(size_t)MDIM * KDIM];

__device__ __forceinline__ void gload_lds16(void* lds, const void* g) {
  __builtin_amdgcn_global_load_lds((const GLOBAL_AS void*)g, (LDS_AS void*)lds, 16, 0, 0);
}

// ---------------------------------------------------------------------------
// scale_kernel: ws[0] = |var| / sum_l exp(-0.5*lam_l)
// ---------------------------------------------------------------------------
__global__ __launch_bounds__(512) void scale_kernel(const float* __restrict__ lam,
                                                    const float* __restrict__ var,
                                                    float* __restrict__ ws) {
  int l = threadIdx.x;
  float v = expf(-0.5f * lam[l]);
  #pragma unroll
  for (int off = 32; off > 0; off >>= 1) v += __shfl_down(v, off, 64);
  __shared__ float red[8];
  if ((l & 63) == 0) red[l >> 6] = v;
  __syncthreads();
  if (l == 0) {
    float t = 0.f;
    #pragma unroll
    for (int i = 0; i < 8; ++i) t += red[i];
    ws[0] = fabsf(var[0]) / t;
  }
}

// ---------------------------------------------------------------------------
// Phase kernel. Blocks 0..511: A rows (8 rows/block, 2 l's/thread, row-major
// bf16 pairs as before). Blocks 512..1535: B cols (4 cols/block; thread
// (c = tid>>6, o = tid&63) computes l = 8o..8o+7 for col, stores cos-octet at
// k=l (octet o) and sin-octet at k=l+512 (octet o+64), 16B dwordx4 each.
// ---------------------------------------------------------------------------
__global__ __launch_bounds__(256) void phase_kernel(const float* __restrict__ x,
                                                    const float* __restrict__ y,
                                                    const float* __restrict__ freqs,
                                                    const float* __restrict__ lam,
                                                    const float* __restrict__ ws) {
  int tid = threadIdx.x;
  int blk = blockIdx.x;
  if (blk < 512) {
    // ---- A part (weighted rows) ----
    int l0 = 2 * tid;
    float s = ws[0];
    float w0 = expf(-0.5f * lam[l0]);
    float w1 = expf(-0.5f * lam[l0 + 1]);
    float a0 = freqs[l0 * 3 + 0], a1 = freqs[l0 * 3 + 1], a2 = freqs[l0 * 3 + 2];
    float b0 = freqs[l0 * 3 + 3], b1 = freqs[l0 * 3 + 4], b2 = freqs[l0 * 3 + 5];
    int r0 = blk * PH_ROWS;
    float g0 = w0 * s, g1 = w1 * s;
    #pragma unroll
    for (int j = 0; j < PH_ROWS; ++j) {
      int rr = r0 + j;
      float p0 = x[rr * 3 + 0], p1 = x[rr * 3 + 1], p2 = x[rr * 3 + 2];
      float px0 = p0 * a0 + p1 * a1 + p2 * a2;
      float px1 = p0 * b0 + p1 * b1 + p2 * b2;
      float sn0, cs0, sn1, cs1;
      __sincosf(px0, &sn0, &cs0);
      __sincosf(px1, &sn1, &cs1);
      __hip_bfloat16* dst = g_A + (size_t)rr * KDIM;
      __hip_bfloat162 cpair, spair;
      cpair.x = __float2bfloat16(g0 * cs0); cpair.y = __float2bfloat16(g1 * cs1);
      spair.x = __float2bfloat16(g0 * sn0); spair.y = __float2bfloat16(g1 * sn1);
      *(__hip_bfloat162*)&dst[l0]        = cpair;
      *(__hip_bfloat162*)&dst[LDIM + l0] = spair;
    }
  } else {
    // ---- B part (unweighted cols, transposed-blocked layout) ----
    int col = (blk - 512) * 4 + (tid >> 6);
    int o   = tid & 63;                     // l-octet 0..63
    float p0 = y[col * 3 + 0], p1 = y[col * 3 + 1], p2 = y[col * 3 + 2];
    bf16x8 co, so;
    #pragma unroll
    for (int i = 0; i < 8; ++i) {
      int li = o * 8 + i;
      float px = p0 * freqs[3 * li] + p1 * freqs[3 * li + 1] + p2 * freqs[3 * li + 2];
      float sn, cs; __sincosf(px, &sn, &cs);
      union { __hip_bfloat16 h; short u; } c_, s_;
      c_.h = __float2bfloat16(cs); s_.h = __float2bfloat16(sn);
      co[i] = c_.u; so[i] = s_.u;
    }
    short* base = (short*)g_Bt + (size_t)col * 8;
    *(bf16x8*)(base + (size_t)o * (MDIM * 8))        = co;   // k = l
    *(bf16x8*)(base + (size_t)(o + 64) * (MDIM * 8)) = so;   // k = l + 512
  }
}

// ---------------------------------------------------------------------------
// GEMM: C = A @ B^T, bf16, K=1024. R5 skeleton + transposed-blocked B in regs.
// 256x256 tile, BK=64, 8 waves (2Mx4N). A in LDS (64 KiB, 2-deep, swizzled,
// staged 2 phases ahead via gload_lds, AREAD 1 phase ahead, LGKM(8)).
// B global->reg, coalesced (4x256B segs/load), prefetched 1 phase ahead.
// 2 phases/tile, 32 MFMA/phase, 1 barrier/phase, VMCNT(6) steady (never 0).
// ---------------------------------------------------------------------------
__global__ __launch_bounds__(512, 2) void gemm_kernel(float* __restrict__ C) {
  __shared__ __align__(16) short Al[2][2][256 * 32];   // 64 KiB

  int bid = blockIdx.x;                   // 0..255
  int xcd = bid & 7;                      // supertile map (R10, verified)
  int slt = bid >> 3;
  int sup = 2 * xcd + (slt >> 4);
  int w_  = slt & 15;
  int brow = ((sup >> 2) * 4 + (w_ >> 2)) * 256;
  int bcol = ((sup & 3) * 4 + (w_ & 3)) * 256;

  int tid  = threadIdx.x;
  int lane = tid & 63;
  int wid  = tid >> 6;                    // 0..7
  int wm   = wid >> 2;                    // 0..1
  int wn   = wid & 3;                     // 0..3

  // A ds_read offsets (R5 swizzle: byte ^= ((row>>1)&3)<<4 within 64B rows)
  int fr   = lane & 15;
  int cs_  = ((lane >> 4) * 16) ^ (((fr >> 1) & 3) << 4);
  int offA0 = (wm * 128 + fr) * 64 + cs_;

  // A staging constants (pre-swizzled global source; LDS dest linear)
  int srow = tid >> 2;                                        // 0..127
  int scb  = ((tid & 3) * 16) ^ (((srow >> 1) & 3) << 4);
  const short* gA = (const short*)g_A + (size_t)(brow + srow) * KDIM + scb / 2;

  // B fragment base: octet index (lane>>4), col = bcol + wn*64 + fr
  const short* gBw = (const short*)g_Bt
                     + (size_t)(lane >> 4) * (MDIM * 8)
                     + (size_t)(bcol + wn * 64 + fr) * 8;

  f32x4 acc[8][4] = {};
  bf16x8 s0_0, s0_1, s0_2, s0_3, s0_4, s0_5, s0_6, s0_7;   // A set 0
  bf16x8 s1_0, s1_1, s1_2, s1_3, s1_4, s1_5, s1_6, s1_7;   // A set 1
  bf16x8 u0, u1, u2, u3;                                   // B set U
  bf16x8 v0, v1, v2, v3;                                   // B set V

#define STAGE(T1, KK)                                                        \
  {                                                                          \
    char* d_ = (char*)(&Al[(T1) & 1][(KK)][0]) + wid * 1024;                 \
    const short* s_ = gA + (T1) * 64 + (KK) * 32;                            \
    gload_lds16(d_, s_);                                                     \
    gload_lds16(d_ + 8192, s_ + (size_t)128 * KDIM);                         \
  }

#define VMCNT(N) asm volatile("s_waitcnt vmcnt(" #N ")" ::: "memory")
#define LGKM(N)  asm volatile("s_waitcnt lgkmcnt(" #N ")" ::: "memory")
#define SCHED0   __builtin_amdgcn_sched_barrier(0)
#define BAR      __builtin_amdgcn_s_barrier()

#define AREAD(S, T, KK)                                                      \
  { const char* Ab_ = (const char*)(&Al[(T) & 1][(KK)][0]);                  \
    S##0 = *(const bf16x8*)(Ab_ + offA0 + 0 * 1024);                         \
    S##1 = *(const bf16x8*)(Ab_ + offA0 + 1 * 1024);                         \
    S##2 = *(const bf16x8*)(Ab_ + offA0 + 2 * 1024);                         \
    S##3 = *(const bf16x8*)(Ab_ + offA0 + 3 * 1024);                         \
    S##4 = *(const bf16x8*)(Ab_ + offA0 + 4 * 1024);                         \
    S##5 = *(const bf16x8*)(Ab_ + offA0 + 5 * 1024);                         \
    S##6 = *(const bf16x8*)(Ab_ + offA0 + 6 * 1024);                         \
    S##7 = *(const bf16x8*)(Ab_ + offA0 + 7 * 1024); }

  // k-octet block for (T,KK): (T*8 + KK*4) blocks of MDIM*8 shorts; n-step 128
#define BGLOB(B0, B1, B2, B3, T, KK)                                         \
  { const short* p_ = gBw + (size_t)((T) * 8 + (KK) * 4) * (MDIM * 8);       \
    B0 = *(const bf16x8*)(p_);                                               \
    B1 = *(const bf16x8*)(p_ + 128);                                         \
    B2 = *(const bf16x8*)(p_ + 256);                                         \
    B3 = *(const bf16x8*)(p_ + 384); }

#define MFMA4(I, AF, B0, B1, B2, B3)                                                  \
  acc[I][0] = __builtin_amdgcn_mfma_f32_16x16x32_bf16(AF, B0, acc[I][0], 0, 0, 0);    \
  acc[I][1] = __builtin_amdgcn_mfma_f32_16x16x32_bf16(AF, B1, acc[I][1], 0, 0, 0);    \
  acc[I][2] = __builtin_amdgcn_mfma_f32_16x16x32_bf16(AF, B2, acc[I][2], 0, 0, 0);    \
  acc[I][3] = __builtin_amdgcn_mfma_f32_16x16x32_bf16(AF, B3, acc[I][3], 0, 0, 0);

#define MFMA32(S, B0, B1, B2, B3)                                            \
  __builtin_amdgcn_s_setprio(1);                                             \
  MFMA4(0, S##0, B0, B1, B2, B3) MFMA4(1, S##1, B0, B1, B2, B3)              \
  MFMA4(2, S##2, B0, B1, B2, B3) MFMA4(3, S##3, B0, B1, B2, B3)              \
  MFMA4(4, S##4, B0, B1, B2, B3) MFMA4(5, S##5, B0, B1, B2, B3)              \
  MFMA4(6, S##6, B0, B1, B2, B3) MFMA4(7, S##7, B0, B1, B2, B3)              \
  __builtin_amdgcn_s_setprio(0);

  // ---- prologue: SA(0,0) SA(0,1) SA(1,0) + Bu(0,0) ----
  STAGE(0, 0);
  STAGE(0, 1);
  STAGE(1, 0);
  BGLOB(u0, u1, u2, u3, 0, 0);
  SCHED0;
  VMCNT(6);                      // tile-0 A slabs landed; SA(1,0)+Bu in flight
  BAR;
  AREAD(s0_, 0, 0);

  // ---- main loop t = 0..13 uniform; peel t = 14, 15 ----
  for (int t = 0; t < 14; ++t) {
    // ph0: compute s0_ x U; read-ahead A(t,1); prefetch B(t,1)->V
    AREAD(s1_, t, 1);
    BGLOB(v0, v1, v2, v3, t, 1);
    SCHED0;
    LGKM(8); SCHED0;
    MFMA32(s0_, u0, u1, u2, u3);
    STAGE(t + 1, 1);
    VMCNT(6);                    // retire SA(t+1,0); leave Bv4+SA(t+1,1)2
    BAR;
    // ph1: compute s1_ x V; read-ahead A(t+1,0); prefetch B(t+1,0)->U
    AREAD(s0_, t + 1, 0);
    BGLOB(u0, u1, u2, u3, t + 1, 0);
    SCHED0;
    LGKM(8); SCHED0;
    MFMA32(s1_, v0, v1, v2, v3);
    STAGE(t + 2, 0);
    VMCNT(6);                    // retire SA(t+1,1); leave Bu4+SA(t+2,0)2
    BAR;
  }
  // t = 14
  AREAD(s1_, 14, 1);
  BGLOB(v0, v1, v2, v3, 14, 1);
  SCHED0;
  LGKM(8); SCHED0;
  MFMA32(s0_, u0, u1, u2, u3);
  STAGE(15, 1);
  VMCNT(6);
  BAR;
  AREAD(s0_, 15, 0);
  BGLOB(u0, u1, u2, u3, 15, 0);
  SCHED0;
  LGKM(8); SCHED0;
  MFMA32(s1_, v0, v1, v2, v3);
  VMCNT(4);                      // retire SA(15,1); leave Bu(15,0)4
  BAR;
  // t = 15
  AREAD(s1_, 15, 1);
  BGLOB(v0, v1, v2, v3, 15, 1);
  SCHED0;
  LGKM(8); SCHED0;
  MFMA32(s0_, u0, u1, u2, u3);
  LGKM(0); SCHED0;
  MFMA32(s1_, v0, v1, v2, v3);

  // ---- epilogue: C/D layout col=lane&15, row=(lane>>4)*4+j ----
  int crow = brow + wm * 128 + (lane >> 4) * 4;
  int ccol = bcol + wn * 64 + (lane & 15);
  #pragma unroll
  for (int mi = 0; mi < 8; ++mi)
    #pragma unroll
    for (int n = 0; n < 4; ++n)
      #pragma unroll
      for (int j = 0; j < 4; ++j)
        C[(size_t)(crow + mi * 16 + j) * MDIM + (ccol + n * 16)] = acc[mi][n][j];
}

extern "C" void kernel_launch(void* const* d_in, const int* in_sizes, int n_in,
                              void* d_out, int out_size, void* d_ws, size_t ws_size,
                              hipStream_t stream) {
  const float* x     = (const float*)d_in[0];
  const float* y     = (const float*)d_in[1];
  const float* freqs = (const float*)d_in[2];
  const float* lam   = (const float*)d_in[3];
  const float* var   = (const float*)d_in[4];
  float* out = (float*)d_out;
  float* ws  = (float*)d_ws;

  hipLaunchKernelGGL(scale_kernel, dim3(1), dim3(512), 0, stream, lam, var, ws);
  hipLaunchKernelGGL(phase_kernel, dim3(512 + MDIM / 4), dim3(256), 0, stream,
                     x, y, freqs, lam, ws);
  hipLaunchKernelGGL(gemm_kernel, dim3((NDIM / 256) * (MDIM / 256)), dim3(512), 0, stream,
                     out);
}

// Round 13
// 54.280 us; speedup vs baseline: 1.5320x; 1.1226x over previous
//
#include <hip/hip_runtime.h>
#include <hip/hip_bf16.h>
#include <math.h>

#define NDIM 4096
#define MDIM 4096
#define LDIM 512
#define KDIM 1024

typedef float f32x4 __attribute__((ext_vector_type(4)));

// Transposed-blocked fp8 operands: [k>>3][point][k&7] -> long per (octet,point)
__device__ __align__(16) unsigned long long g_At[(size_t)128 * NDIM];
__device__ __align__(16) unsigned long long g_Bt[(size_t)128 * MDIM];

// ---------------------------------------------------------------------------
// scale_kernel: ws[0] = |var| / sum_l exp(-0.5*lam_l)
// ---------------------------------------------------------------------------
__global__ __launch_bounds__(512) void scale_kernel(const float* __restrict__ lam,
                                                    const float* __restrict__ var,
                                                    float* __restrict__ ws) {
  int l = threadIdx.x;
  float v = expf(-0.5f * lam[l]);
  #pragma unroll
  for (int off = 32; off > 0; off >>= 1) v += __shfl_down(v, off, 64);
  __shared__ float red[8];
  if ((l & 63) == 0) red[l >> 6] = v;
  __syncthreads();
  if (l == 0) {
    float t = 0.f;
    #pragma unroll
    for (int i = 0; i < 8; ++i) t += red[i];
    ws[0] = fabsf(var[0]) / t;
  }
}

// ---------------------------------------------------------------------------
// Phase kernel: thread -> (point p, octet o). Computes 8 l's (l = 8o..8o+7):
// cos-octet -> k-octet o, sin-octet -> k-octet o+64, fp8 e4m3 packed 8B.
// A rows (p<4096): multiplied by w_l = exp(-0.5 lam). B cols: unweighted.
// Lanes 0..63 = consecutive points -> 512B contiguous stores per wave.
// Grid: 2048 blocks x 256 thr = 8192 points x 64/4... block covers 64 points
// x 4 octets: p = (blk&127)*64 + (tid&63), o = (blk>>7)*4 + (tid>>6).
// ---------------------------------------------------------------------------
__global__ __launch_bounds__(256) void phase_kernel(const float* __restrict__ x,
                                                    const float* __restrict__ y,
                                                    const float* __restrict__ freqs,
                                                    const float* __restrict__ lam) {
  int tid = threadIdx.x;
  int blk = blockIdx.x;
  int p = (blk & 127) * 64 + (tid & 63);
  int o = (blk >> 7) * 4 + (tid >> 6);
  bool isA = (p < NDIM);
  int rr = isA ? p : (p - NDIM);
  const float* pt = (isA ? x : y) + 3 * (size_t)rr;
  float p0 = pt[0], p1 = pt[1], p2 = pt[2];

  float cv[8], sv[8];
  #pragma unroll
  for (int i = 0; i < 8; ++i) {
    int li = o * 8 + i;
    float px = p0 * freqs[3 * li] + p1 * freqs[3 * li + 1] + p2 * freqs[3 * li + 2];
    float sn, cs;
    __sincosf(px, &sn, &cs);
    float wl = isA ? expf(-0.5f * lam[li]) : 1.0f;
    cv[i] = cs * wl;
    sv[i] = sn * wl;
  }
  union { int i2[2]; unsigned long long u; } pc, ps;
  pc.i2[0] = __builtin_amdgcn_cvt_pk_fp8_f32(cv[0], cv[1], 0, 0);
  pc.i2[0] = __builtin_amdgcn_cvt_pk_fp8_f32(cv[2], cv[3], pc.i2[0], 1);
  pc.i2[1] = __builtin_amdgcn_cvt_pk_fp8_f32(cv[4], cv[5], 0, 0);
  pc.i2[1] = __builtin_amdgcn_cvt_pk_fp8_f32(cv[6], cv[7], pc.i2[1], 1);
  ps.i2[0] = __builtin_amdgcn_cvt_pk_fp8_f32(sv[0], sv[1], 0, 0);
  ps.i2[0] = __builtin_amdgcn_cvt_pk_fp8_f32(sv[2], sv[3], ps.i2[0], 1);
  ps.i2[1] = __builtin_amdgcn_cvt_pk_fp8_f32(sv[4], sv[5], 0, 0);
  ps.i2[1] = __builtin_amdgcn_cvt_pk_fp8_f32(sv[6], sv[7], ps.i2[1], 1);

  unsigned long long* base = (isA ? g_At : g_Bt) + rr;
  base[(size_t)o * NDIM]        = pc.u;   // k-octet o       (cos)
  base[(size_t)(o + 64) * NDIM] = ps.u;   // k-octet o + 64  (sin)
}

// ---------------------------------------------------------------------------
// GEMM: C = s * (A @ B^T), fp8 e4m3 operands, K=1024. NO LDS, NO BARRIERS:
// every 16x16x32 fragment is one coalesced b64 load from the transposed-
// blocked layout (lane: row/col = base+fr, k-octet = lane>>4). Waves fully
// independent; half-tile (K=32) software pipeline with named double buffers.
// 256x256 tile, 8 waves 2Mx4N, wave 128x64, acc 8x4. s applied in epilogue.
// ---------------------------------------------------------------------------
__global__ __launch_bounds__(512, 2) void gemm_kernel(float* __restrict__ C,
                                                      const float* __restrict__ ws) {
  int bid = blockIdx.x;                   // 0..255
  int xcd = bid & 7;                      // supertile map (R10/R12, verified)
  int slt = bid >> 3;
  int sup = 2 * xcd + (slt >> 4);
  int w_  = slt & 15;
  int brow = ((sup >> 2) * 4 + (w_ >> 2)) * 256;
  int bcol = ((sup & 3) * 4 + (w_ & 3)) * 256;

  int tid  = threadIdx.x;
  int lane = tid & 63;
  int wid  = tid >> 6;                    // 0..7
  int wm   = wid >> 2;                    // 0..1
  int wn   = wid & 3;                     // 0..3
  int fr   = lane & 15;
  int oct  = lane >> 4;                   // 0..3

  float s_val = ws[0];

  // frag (h, m): At[(h*4)*NDIM + m*16]  (h = half-tile 0..31, k-oct = h*4+oct)
  const unsigned long long* At = g_At + (size_t)oct * NDIM + (brow + wm * 128 + fr);
  const unsigned long long* Bt = g_Bt + (size_t)oct * MDIM + (bcol + wn * 64 + fr);

  f32x4 acc[8][4] = {};
  long pa0, pa1, pa2, pa3, pa4, pa5, pa6, pa7, pb0, pb1, pb2, pb3;
  long qa0, qa1, qa2, qa3, qa4, qa5, qa6, qa7, qb0, qb1, qb2, qb3;

#define LOADH(S, H)                                                          \
  { const unsigned long long* Ap_ = At + (size_t)(H) * 4 * NDIM;             \
    const unsigned long long* Bp_ = Bt + (size_t)(H) * 4 * MDIM;             \
    S##a0 = (long)Ap_[0];   S##a1 = (long)Ap_[16];                           \
    S##a2 = (long)Ap_[32];  S##a3 = (long)Ap_[48];                           \
    S##a4 = (long)Ap_[64];  S##a5 = (long)Ap_[80];                           \
    S##a6 = (long)Ap_[96];  S##a7 = (long)Ap_[112];                          \
    S##b0 = (long)Bp_[0];   S##b1 = (long)Bp_[16];                           \
    S##b2 = (long)Bp_[32];  S##b3 = (long)Bp_[48]; }

#define MFH1(M, AF, S)                                                       \
  acc[M][0] = __builtin_amdgcn_mfma_f32_16x16x32_fp8_fp8(AF, S##b0, acc[M][0], 0, 0, 0); \
  acc[M][1] = __builtin_amdgcn_mfma_f32_16x16x32_fp8_fp8(AF, S##b1, acc[M][1], 0, 0, 0); \
  acc[M][2] = __builtin_amdgcn_mfma_f32_16x16x32_fp8_fp8(AF, S##b2, acc[M][2], 0, 0, 0); \
  acc[M][3] = __builtin_amdgcn_mfma_f32_16x16x32_fp8_fp8(AF, S##b3, acc[M][3], 0, 0, 0);

#define MFH(S)                                                               \
  MFH1(0, S##a0, S) MFH1(1, S##a1, S) MFH1(2, S##a2, S) MFH1(3, S##a3, S)    \
  MFH1(4, S##a4, S) MFH1(5, S##a5, S) MFH1(6, S##a6, S) MFH1(7, S##a7, S)

  // ---- software pipeline over 32 half-tiles, 1 half-tile prefetch ----
  LOADH(p, 0);
  for (int hh = 0; hh < 15; ++hh) {
    LOADH(q, 2 * hh + 1);
    MFH(p);
    LOADH(p, 2 * hh + 2);
    MFH(q);
  }
  LOADH(q, 31);
  MFH(p);
  MFH(q);

  // ---- epilogue: out = s * acc; C/D layout col=lane&15, row=(lane>>4)*4+j --
  int crow = brow + wm * 128 + (lane >> 4) * 4;
  int ccol = bcol + wn * 64 + (lane & 15);
  #pragma unroll
  for (int mi = 0; mi < 8; ++mi)
    #pragma unroll
    for (int n = 0; n < 4; ++n)
      #pragma unroll
      for (int j = 0; j < 4; ++j)
        C[(size_t)(crow + mi * 16 + j) * MDIM + (ccol + n * 16)] = s_val * acc[mi][n][j];
}

extern "C" void kernel_launch(void* const* d_in, const int* in_sizes, int n_in,
                              void* d_out, int out_size, void* d_ws, size_t ws_size,
                              hipStream_t stream) {
  const float* x     = (const float*)d_in[0];
  const float* y     = (const float*)d_in[1];
  const float* freqs = (const float*)d_in[2];
  const float* lam   = (const float*)d_in[3];
  const float* var   = (const float*)d_in[4];
  float* out = (float*)d_out;
  float* ws  = (float*)d_ws;

  hipLaunchKernelGGL(scale_kernel, dim3(1), dim3(512), 0, stream, lam, var, ws);
  hipLaunchKernelGGL(phase_kernel, dim3(2048), dim3(256), 0, stream,
                     x, y, freqs, lam);
  hipLaunchKernelGGL(gemm_kernel, dim3((NDIM / 256) * (MDIM / 256)), dim3(512), 0, stream,
                     out, ws);
}